// Round 1
// baseline (634.485 us; speedup 1.0000x reference)
//
#include <hip/hip_runtime.h>

// ---------------------------------------------------------------------------
// CustomMultiHeadAttention: B=2, N=2048, E=768, H=12, HD=64
// out = (softmax(Q K^T / 8) V) proj;  outputs = [out (2,2048,768) fp32 ;
//                                               attn_probs (2,12,2048,2048) fp32]
// Plan: bf16 MFMA for all matmuls (fp32 accumulate), two-pass exact softmax.
// ---------------------------------------------------------------------------

typedef __bf16 bf16x8 __attribute__((ext_vector_type(8)));
typedef float  f32x4  __attribute__((ext_vector_type(4)));

__device__ __forceinline__ unsigned short f2bf(float f) {
  union { float f; unsigned int u; } v; v.f = f;
  unsigned int r = v.u + 0x7FFFu + ((v.u >> 16) & 1u);   // RTNE
  return (unsigned short)(r >> 16);
}

// ---------------------------------------------------------------------------
// GEMM: C[M,N] = A[M,K] @ B[K,N] + bias  (A fp32 or bf16; C fp32 or bf16)
// 128x128 tile, BK=32, 4 waves (2x2), each wave 64x64 via 4x4 mfma 16x16x32.
// ---------------------------------------------------------------------------
template<bool A_BF16, bool OUT_BF16>
__global__ __launch_bounds__(256) void gemm_bias_kernel(
    const void* __restrict__ Av, const float* __restrict__ B,
    const float* __restrict__ bias, void* __restrict__ Cv,
    int M, int N, int K)
{
  __shared__ __align__(16) unsigned short Alds[128][40];  // +8 pad: kills bank conflicts
  __shared__ __align__(16) unsigned short Btl [128][40];  // B transposed [n][k]

  const int tid  = threadIdx.x;
  const int lane = tid & 63;
  const int w    = tid >> 6;
  const int wr   = w >> 1, wc = w & 1;
  const int l16  = lane & 15, lg = lane >> 4;
  const int tn   = blockIdx.x, tm = blockIdx.y;

  f32x4 acc[4][4];
#pragma unroll
  for (int m = 0; m < 4; ++m)
#pragma unroll
    for (int n = 0; n < 4; ++n) acc[m][n] = (f32x4){0.f, 0.f, 0.f, 0.f};

  const int nkt = K >> 5;
  for (int kt = 0; kt < nkt; ++kt) {
    // ---- stage A tile [128][32] -> bf16 LDS ----
    if (A_BF16) {
      const unsigned short* A = (const unsigned short*)Av;
#pragma unroll
      for (int it = 0; it < 2; ++it) {
        int id = tid + it * 256;
        int r = id >> 2, c8 = id & 3;
        *(uint4*)&Alds[r][c8 * 8] =
            *(const uint4*)(A + (size_t)(tm * 128 + r) * K + kt * 32 + c8 * 8);
      }
    } else {
      const float* A = (const float*)Av;
#pragma unroll
      for (int it = 0; it < 4; ++it) {
        int id = tid + it * 256;
        int r = id >> 3, c4 = id & 7;
        const float4 v = *(const float4*)(A + (size_t)(tm * 128 + r) * K + kt * 32 + c4 * 4);
        ushort4 u;
        u.x = f2bf(v.x); u.y = f2bf(v.y); u.z = f2bf(v.z); u.w = f2bf(v.w);
        *(ushort4*)&Alds[r][c4 * 4] = u;
      }
    }
    // ---- stage B tile [32][128] transposed -> Btl[n][k] bf16 ----
#pragma unroll
    for (int it = 0; it < 4; ++it) {
      int id = tid + it * 256;
      int k = id >> 5, c4 = id & 31;
      const float4 v = *(const float4*)(B + (size_t)(kt * 32 + k) * N + tn * 128 + c4 * 4);
      Btl[c4 * 4 + 0][k] = f2bf(v.x);
      Btl[c4 * 4 + 1][k] = f2bf(v.y);
      Btl[c4 * 4 + 2][k] = f2bf(v.z);
      Btl[c4 * 4 + 3][k] = f2bf(v.w);
    }
    __syncthreads();

    bf16x8 af[4], bfr[4];
#pragma unroll
    for (int m = 0; m < 4; ++m)
      af[m] = *(const bf16x8*)&Alds[wr * 64 + m * 16 + l16][lg * 8];
#pragma unroll
    for (int n = 0; n < 4; ++n)
      bfr[n] = *(const bf16x8*)&Btl[wc * 64 + n * 16 + l16][lg * 8];
#pragma unroll
    for (int m = 0; m < 4; ++m)
#pragma unroll
      for (int n = 0; n < 4; ++n)
        acc[m][n] = __builtin_amdgcn_mfma_f32_16x16x32_bf16(af[m], bfr[n], acc[m][n], 0, 0, 0);
    __syncthreads();
  }

  // ---- epilogue: bias add, store ----
#pragma unroll
  for (int n = 0; n < 4; ++n) {
    const int col = tn * 128 + wc * 64 + n * 16 + l16;
    const float bv = bias[col];
#pragma unroll
    for (int m = 0; m < 4; ++m) {
#pragma unroll
      for (int rr = 0; rr < 4; ++rr) {
        const int row = tm * 128 + wr * 64 + m * 16 + lg * 4 + rr;
        const float val = acc[m][n][rr] + bv;
        if (OUT_BF16) ((unsigned short*)Cv)[(size_t)row * N + col] = f2bf(val);
        else          ((float*)Cv)[(size_t)row * N + col] = val;
      }
    }
  }
}

// ---------------------------------------------------------------------------
// Attention: per (b*h, 64-row q-tile). Two-pass exact softmax (no max-sub:
// scores <= ~6). Pass1: row sums of exp(S). Pass2: recompute S, write probs,
// accumulate P@V. qkv is bf16 [B*N][2304] laid out [q|k|v] x [H][HD].
// ---------------------------------------------------------------------------
__global__ __launch_bounds__(256) void attn_kernel(
    const unsigned short* __restrict__ qkv,
    float* __restrict__ probs,
    unsigned short* __restrict__ attn_out)
{
  __shared__ __align__(16) unsigned short Kl [64][72];  // K tile [pos][hd], +8 pad
  __shared__ __align__(16) unsigned short VTl[64][72];  // V^T tile [hd][pos]
  __shared__ __align__(16) unsigned short Pl [64][72];  // P tile [qrow][pos]

  const int bh = blockIdx.x, qt = blockIdx.y;
  const int b = bh / 12, h = bh % 12;
  const int tid = threadIdx.x;
  const int lane = tid & 63, w = tid >> 6;
  const int l16 = lane & 15, lg = lane >> 4;
  const float scale = 0.125f;

  // Q fragments live in registers for the whole kernel (wave owns 16 q-rows)
  const size_t qoff = ((size_t)b * 2048 + qt * 64 + w * 16 + l16) * 2304 + h * 64 + lg * 8;
  const bf16x8 qf0 = *(const bf16x8*)(qkv + qoff);
  const bf16x8 qf1 = *(const bf16x8*)(qkv + qoff + 32);

  // ---------------- pass 1: row sums of exp(S) ----------------
  float rs[4] = {0.f, 0.f, 0.f, 0.f};
  for (int kt = 0; kt < 32; ++kt) {
#pragma unroll
    for (int it = 0; it < 2; ++it) {
      int id = tid + it * 256;
      int p = id >> 3, c8 = id & 7;
      *(uint4*)&Kl[p][c8 * 8] =
          *(const uint4*)(qkv + ((size_t)b * 2048 + kt * 64 + p) * 2304 + 768 + h * 64 + c8 * 8);
    }
    __syncthreads();
#pragma unroll
    for (int n = 0; n < 4; ++n) {
      const bf16x8 kf0 = *(const bf16x8*)&Kl[n * 16 + l16][lg * 8];
      const bf16x8 kf1 = *(const bf16x8*)&Kl[n * 16 + l16][32 + lg * 8];
      f32x4 s = (f32x4){0.f, 0.f, 0.f, 0.f};
      s = __builtin_amdgcn_mfma_f32_16x16x32_bf16(qf0, kf0, s, 0, 0, 0);
      s = __builtin_amdgcn_mfma_f32_16x16x32_bf16(qf1, kf1, s, 0, 0, 0);
#pragma unroll
      for (int rr = 0; rr < 4; ++rr) rs[rr] += __expf(s[rr] * scale);
    }
    __syncthreads();
  }
  // reduce over the 16 lanes sharing the same 4 rows; then invert
#pragma unroll
  for (int rr = 0; rr < 4; ++rr) {
    rs[rr] += __shfl_xor(rs[rr], 1);
    rs[rr] += __shfl_xor(rs[rr], 2);
    rs[rr] += __shfl_xor(rs[rr], 4);
    rs[rr] += __shfl_xor(rs[rr], 8);
    rs[rr] = 1.0f / rs[rr];
  }

  // ---------------- pass 2: probs + P@V ----------------
  f32x4 oacc[4];
#pragma unroll
  for (int n = 0; n < 4; ++n) oacc[n] = (f32x4){0.f, 0.f, 0.f, 0.f};

  for (int kt = 0; kt < 32; ++kt) {
#pragma unroll
    for (int it = 0; it < 2; ++it) {
      int id = tid + it * 256;
      int p = id >> 3, c8 = id & 7;
      const size_t base = ((size_t)b * 2048 + kt * 64 + p) * 2304 + h * 64 + c8 * 8;
      *(uint4*)&Kl[p][c8 * 8] = *(const uint4*)(qkv + base + 768);
      uint4 vv = *(const uint4*)(qkv + base + 1536);
      const unsigned short* vs = (const unsigned short*)&vv;
#pragma unroll
      for (int j = 0; j < 8; ++j) VTl[c8 * 8 + j][p] = vs[j];  // transpose V into LDS
    }
    __syncthreads();

#pragma unroll
    for (int n = 0; n < 4; ++n) {
      const bf16x8 kf0 = *(const bf16x8*)&Kl[n * 16 + l16][lg * 8];
      const bf16x8 kf1 = *(const bf16x8*)&Kl[n * 16 + l16][32 + lg * 8];
      f32x4 s = (f32x4){0.f, 0.f, 0.f, 0.f};
      s = __builtin_amdgcn_mfma_f32_16x16x32_bf16(qf0, kf0, s, 0, 0, 0);
      s = __builtin_amdgcn_mfma_f32_16x16x32_bf16(qf1, kf1, s, 0, 0, 0);
#pragma unroll
      for (int rr = 0; rr < 4; ++rr) {
        const float p = __expf(s[rr] * scale) * rs[rr];
        const int qr = qt * 64 + w * 16 + lg * 4 + rr;
        probs[((size_t)bh * 2048 + qr) * 2048 + (size_t)kt * 64 + n * 16 + l16] = p;
        Pl[w * 16 + lg * 4 + rr][n * 16 + l16] = f2bf(p);
      }
    }
    __syncthreads();

    const bf16x8 pa0 = *(const bf16x8*)&Pl[w * 16 + l16][lg * 8];
    const bf16x8 pa1 = *(const bf16x8*)&Pl[w * 16 + l16][32 + lg * 8];
#pragma unroll
    for (int n = 0; n < 4; ++n) {
      const bf16x8 vb0 = *(const bf16x8*)&VTl[n * 16 + l16][lg * 8];
      const bf16x8 vb1 = *(const bf16x8*)&VTl[n * 16 + l16][32 + lg * 8];
      oacc[n] = __builtin_amdgcn_mfma_f32_16x16x32_bf16(pa0, vb0, oacc[n], 0, 0, 0);
      oacc[n] = __builtin_amdgcn_mfma_f32_16x16x32_bf16(pa1, vb1, oacc[n], 0, 0, 0);
    }
    __syncthreads();
  }

  // write attn context (bf16) to workspace: [B*N][768] at col h*64+...
#pragma unroll
  for (int n = 0; n < 4; ++n)
#pragma unroll
    for (int rr = 0; rr < 4; ++rr) {
      const int qr = qt * 64 + w * 16 + lg * 4 + rr;
      attn_out[((size_t)b * 2048 + qr) * 768 + h * 64 + n * 16 + l16] = f2bf(oacc[n][rr]);
    }
}

// ---------------------------------------------------------------------------
extern "C" void kernel_launch(void* const* d_in, const int* in_sizes, int n_in,
                              void* d_out, int out_size, void* d_ws, size_t ws_size,
                              hipStream_t stream) {
  const float* x     = (const float*)d_in[0];   // [2,2048,768]
  const float* w_qkv = (const float*)d_in[1];   // [768,2304]
  const float* b_qkv = (const float*)d_in[2];   // [2304]
  const float* w_out = (const float*)d_in[3];   // [768,768]
  const float* b_out = (const float*)d_in[4];   // [768]

  float* out   = (float*)d_out;                 // [2,2048,768] = 3145728 floats
  float* probs = out + 3145728;                 // [2,12,2048,2048]

  unsigned short* qkv_ws  = (unsigned short*)d_ws;          // bf16 [4096][2304]
  unsigned short* attn_ws = qkv_ws + (size_t)4096 * 2304;   // bf16 [4096][768]

  // 1) QKV projection: [4096,768] @ [768,2304] + b -> bf16 qkv
  gemm_bias_kernel<false, true><<<dim3(18, 32), 256, 0, stream>>>(
      (const void*)x, w_qkv, b_qkv, (void*)qkv_ws, 4096, 2304, 768);

  // 2) attention: probs (fp32, to d_out) + context (bf16, to ws)
  attn_kernel<<<dim3(24, 32), 256, 0, stream>>>(qkv_ws, probs, attn_ws);

  // 3) output projection: [4096,768] @ [768,768] + b -> fp32 out
  gemm_bias_kernel<true, false><<<dim3(6, 32), 256, 0, stream>>>(
      (const void*)attn_ws, w_out, b_out, (void*)out, 4096, 768, 768);
}

// Round 2
// 633.298 us; speedup vs baseline: 1.0019x; 1.0019x over previous
//
#include <hip/hip_runtime.h>

// ---------------------------------------------------------------------------
// CustomMultiHeadAttention: B=2, N=2048, E=768, H=12, HD=64
// outputs = [out (2,2048,768) fp32 ; attn_probs (2,12,2048,2048) fp32]
// bf16 MFMA everywhere, two-pass exact softmax, swapped QK^T (lane owns q-row)
// ---------------------------------------------------------------------------

typedef __bf16 bf16x8 __attribute__((ext_vector_type(8)));
typedef float  f32x4  __attribute__((ext_vector_type(4)));

__device__ __forceinline__ unsigned short f2bf(float f) {
  union { float f; unsigned int u; } v; v.f = f;
  unsigned int r = v.u + 0x7FFFu + ((v.u >> 16) & 1u);   // RTNE
  return (unsigned short)(r >> 16);
}

// ---------------------------------------------------------------------------
// GEMM: C[M,N] = A[M,K] @ B[K,N] + bias  (A fp32 or bf16; C fp32 or bf16)
// 128x128 tile, BK=32, 4 waves (2x2), each wave 64x64 via 4x4 mfma 16x16x32.
// (unchanged from R1 — passed; attention is the bottleneck this round)
// ---------------------------------------------------------------------------
template<bool A_BF16, bool OUT_BF16>
__global__ __launch_bounds__(256) void gemm_bias_kernel(
    const void* __restrict__ Av, const float* __restrict__ B,
    const float* __restrict__ bias, void* __restrict__ Cv,
    int M, int N, int K)
{
  __shared__ __align__(16) unsigned short Alds[128][40];
  __shared__ __align__(16) unsigned short Btl [128][40];

  const int tid  = threadIdx.x;
  const int lane = tid & 63;
  const int w    = tid >> 6;
  const int wr   = w >> 1, wc = w & 1;
  const int l16  = lane & 15, lg = lane >> 4;
  const int tn   = blockIdx.x, tm = blockIdx.y;

  f32x4 acc[4][4];
#pragma unroll
  for (int m = 0; m < 4; ++m)
#pragma unroll
    for (int n = 0; n < 4; ++n) acc[m][n] = (f32x4){0.f, 0.f, 0.f, 0.f};

  const int nkt = K >> 5;
  for (int kt = 0; kt < nkt; ++kt) {
    if (A_BF16) {
      const unsigned short* A = (const unsigned short*)Av;
#pragma unroll
      for (int it = 0; it < 2; ++it) {
        int id = tid + it * 256;
        int r = id >> 2, c8 = id & 3;
        *(uint4*)&Alds[r][c8 * 8] =
            *(const uint4*)(A + (size_t)(tm * 128 + r) * K + kt * 32 + c8 * 8);
      }
    } else {
      const float* A = (const float*)Av;
#pragma unroll
      for (int it = 0; it < 4; ++it) {
        int id = tid + it * 256;
        int r = id >> 3, c4 = id & 7;
        const float4 v = *(const float4*)(A + (size_t)(tm * 128 + r) * K + kt * 32 + c4 * 4);
        ushort4 u;
        u.x = f2bf(v.x); u.y = f2bf(v.y); u.z = f2bf(v.z); u.w = f2bf(v.w);
        *(ushort4*)&Alds[r][c4 * 4] = u;
      }
    }
#pragma unroll
    for (int it = 0; it < 4; ++it) {
      int id = tid + it * 256;
      int k = id >> 5, c4 = id & 31;
      const float4 v = *(const float4*)(B + (size_t)(kt * 32 + k) * N + tn * 128 + c4 * 4);
      Btl[c4 * 4 + 0][k] = f2bf(v.x);
      Btl[c4 * 4 + 1][k] = f2bf(v.y);
      Btl[c4 * 4 + 2][k] = f2bf(v.z);
      Btl[c4 * 4 + 3][k] = f2bf(v.w);
    }
    __syncthreads();

    bf16x8 af[4], bfr[4];
#pragma unroll
    for (int m = 0; m < 4; ++m)
      af[m] = *(const bf16x8*)&Alds[wr * 64 + m * 16 + l16][lg * 8];
#pragma unroll
    for (int n = 0; n < 4; ++n)
      bfr[n] = *(const bf16x8*)&Btl[wc * 64 + n * 16 + l16][lg * 8];
#pragma unroll
    for (int m = 0; m < 4; ++m)
#pragma unroll
      for (int n = 0; n < 4; ++n)
        acc[m][n] = __builtin_amdgcn_mfma_f32_16x16x32_bf16(af[m], bfr[n], acc[m][n], 0, 0, 0);
    __syncthreads();
  }

#pragma unroll
  for (int n = 0; n < 4; ++n) {
    const int col = tn * 128 + wc * 64 + n * 16 + l16;
    const float bv = bias[col];
#pragma unroll
    for (int m = 0; m < 4; ++m) {
#pragma unroll
      for (int rr = 0; rr < 4; ++rr) {
        const int row = tm * 128 + wr * 64 + m * 16 + lg * 4 + rr;
        const float val = acc[m][n][rr] + bv;
        if (OUT_BF16) ((unsigned short*)Cv)[(size_t)row * N + col] = f2bf(val);
        else          ((float*)Cv)[(size_t)row * N + col] = val;
      }
    }
  }
}

// ---------------------------------------------------------------------------
// Attention v2: swapped QK^T. Per block: (b*h, 64 q-rows), 4 waves x 16 rows.
// S^T = mfma(K-frag, Q-frag): lane (l16,lg) holds S[kpos=n*16+lg*4+rr][qrow=l16]
// -> per-lane row sums, float4 prob stores, b64 P writes.
// ---------------------------------------------------------------------------
__global__ __launch_bounds__(256) void attn_kernel(
    const unsigned short* __restrict__ qkv,
    float* __restrict__ probs,
    unsigned short* __restrict__ attn_out)
{
  __shared__ __align__(16) unsigned short Kl [64][72];  // K [kpos][hd], stride 144B = 16*9
  __shared__ __align__(16) unsigned short VTl[64][88];  // V^T [hd][kpos], stride 176B = 16*11
  __shared__ __align__(16) unsigned short Pl [64][72];  // P [qrow][kpos]

  const int bh = blockIdx.x, qt = blockIdx.y;
  const int b = bh / 12, h = bh % 12;
  const int tid  = threadIdx.x;
  const int lane = tid & 63, w = tid >> 6;
  const int l16  = lane & 15, lg = lane >> 4;

  // Q as MFMA B-operand: lane holds Q[qrow=l16 (of this wave)][d = lg*8 + j]
  const size_t qoff = ((size_t)b * 2048 + qt * 64 + w * 16 + l16) * 2304 + h * 64 + lg * 8;
  const bf16x8 qf0 = *(const bf16x8*)(qkv + qoff);
  const bf16x8 qf1 = *(const bf16x8*)(qkv + qoff + 32);

  // staging maps
  const int sp  = tid >> 3;        // K rows 0..31 (and +32)
  const int sc8 = tid & 7;
  const int vp  = (tid & 31) * 2;  // V row pair (lanes 0..31 span 32 pairs -> all banks)
  const int vc8 = tid >> 5;        // 0..7
  const size_t kbase = (size_t)b * 2048 * 2304 + 768  + h * 64;
  const size_t vbase = (size_t)b * 2048 * 2304 + 1536 + h * 64;

  // ---------------- pass 1: row sums ----------------
  float rs = 0.f;
  for (int kt = 0; kt < 32; ++kt) {
    const size_t rb = kbase + (size_t)kt * 64 * 2304;
    *(uint4*)&Kl[sp][sc8 * 8]      = *(const uint4*)(qkv + rb + (size_t)sp * 2304 + sc8 * 8);
    *(uint4*)&Kl[sp + 32][sc8 * 8] = *(const uint4*)(qkv + rb + (size_t)(sp + 32) * 2304 + sc8 * 8);
    __syncthreads();
#pragma unroll
    for (int n = 0; n < 4; ++n) {
      const bf16x8 kf0 = *(const bf16x8*)&Kl[n * 16 + l16][lg * 8];
      const bf16x8 kf1 = *(const bf16x8*)&Kl[n * 16 + l16][32 + lg * 8];
      f32x4 s = (f32x4){0.f, 0.f, 0.f, 0.f};
      s = __builtin_amdgcn_mfma_f32_16x16x32_bf16(kf0, qf0, s, 0, 0, 0);
      s = __builtin_amdgcn_mfma_f32_16x16x32_bf16(kf1, qf1, s, 0, 0, 0);
      rs += __expf(s[0] * 0.125f) + __expf(s[1] * 0.125f)
          + __expf(s[2] * 0.125f) + __expf(s[3] * 0.125f);
    }
    __syncthreads();
  }
  rs += __shfl_xor(rs, 16);
  rs += __shfl_xor(rs, 32);
  const float rsi = 1.0f / rs;

  // ---------------- pass 2: probs + P@V ----------------
  f32x4 oacc[4];
#pragma unroll
  for (int n = 0; n < 4; ++n) oacc[n] = (f32x4){0.f, 0.f, 0.f, 0.f};

  const size_t prow = ((size_t)bh * 2048 + qt * 64 + w * 16 + l16) * 2048;

  for (int kt = 0; kt < 32; ++kt) {
    const size_t rbk = kbase + (size_t)kt * 64 * 2304;
    const size_t rbv = vbase + (size_t)kt * 64 * 2304;
    // K tile
    *(uint4*)&Kl[sp][sc8 * 8]      = *(const uint4*)(qkv + rbk + (size_t)sp * 2304 + sc8 * 8);
    *(uint4*)&Kl[sp + 32][sc8 * 8] = *(const uint4*)(qkv + rbk + (size_t)(sp + 32) * 2304 + sc8 * 8);
    // V tile, transposed via paired-row b32 writes (conflict-free mapping)
    {
      uint4 v0 = *(const uint4*)(qkv + rbv + (size_t)vp * 2304 + vc8 * 8);
      uint4 v1 = *(const uint4*)(qkv + rbv + (size_t)(vp + 1) * 2304 + vc8 * 8);
      const unsigned short* a0 = (const unsigned short*)&v0;
      const unsigned short* a1 = (const unsigned short*)&v1;
#pragma unroll
      for (int j = 0; j < 8; ++j)
        *(unsigned int*)&VTl[vc8 * 8 + j][vp] =
            (unsigned int)a0[j] | ((unsigned int)a1[j] << 16);
    }
    __syncthreads();

#pragma unroll
    for (int n = 0; n < 4; ++n) {
      const bf16x8 kf0 = *(const bf16x8*)&Kl[n * 16 + l16][lg * 8];
      const bf16x8 kf1 = *(const bf16x8*)&Kl[n * 16 + l16][32 + lg * 8];
      f32x4 s = (f32x4){0.f, 0.f, 0.f, 0.f};
      s = __builtin_amdgcn_mfma_f32_16x16x32_bf16(kf0, qf0, s, 0, 0, 0);
      s = __builtin_amdgcn_mfma_f32_16x16x32_bf16(kf1, qf1, s, 0, 0, 0);
      // lane (l16,lg): qrow = l16, kcols = kt*64 + n*16 + lg*4 + (0..3)
      const float p0 = __expf(s[0] * 0.125f) * rsi;
      const float p1 = __expf(s[1] * 0.125f) * rsi;
      const float p2 = __expf(s[2] * 0.125f) * rsi;
      const float p3 = __expf(s[3] * 0.125f) * rsi;
      *(float4*)&probs[prow + kt * 64 + n * 16 + lg * 4] = (float4){p0, p1, p2, p3};
      uint2 u;
      u.x = (unsigned int)f2bf(p0) | ((unsigned int)f2bf(p1) << 16);
      u.y = (unsigned int)f2bf(p2) | ((unsigned int)f2bf(p3) << 16);
      *(uint2*)&Pl[w * 16 + l16][n * 16 + lg * 4] = u;
    }
    __syncthreads();

    const bf16x8 pa0 = *(const bf16x8*)&Pl[w * 16 + l16][lg * 8];
    const bf16x8 pa1 = *(const bf16x8*)&Pl[w * 16 + l16][32 + lg * 8];
#pragma unroll
    for (int n = 0; n < 4; ++n) {
      const bf16x8 vb0 = *(const bf16x8*)&VTl[n * 16 + l16][lg * 8];
      const bf16x8 vb1 = *(const bf16x8*)&VTl[n * 16 + l16][32 + lg * 8];
      oacc[n] = __builtin_amdgcn_mfma_f32_16x16x32_bf16(pa0, vb0, oacc[n], 0, 0, 0);
      oacc[n] = __builtin_amdgcn_mfma_f32_16x16x32_bf16(pa1, vb1, oacc[n], 0, 0, 0);
    }
    __syncthreads();
  }

  // context write: D[row=lg*4+rr (qrow of wave), col=l16 (d of n-block)]
#pragma unroll
  for (int n = 0; n < 4; ++n)
#pragma unroll
    for (int rr = 0; rr < 4; ++rr) {
      const int qr = qt * 64 + w * 16 + lg * 4 + rr;
      attn_out[((size_t)b * 2048 + qr) * 768 + h * 64 + n * 16 + l16] = f2bf(oacc[n][rr]);
    }
}

// ---------------------------------------------------------------------------
extern "C" void kernel_launch(void* const* d_in, const int* in_sizes, int n_in,
                              void* d_out, int out_size, void* d_ws, size_t ws_size,
                              hipStream_t stream) {
  const float* x     = (const float*)d_in[0];
  const float* w_qkv = (const float*)d_in[1];
  const float* b_qkv = (const float*)d_in[2];
  const float* w_out = (const float*)d_in[3];
  const float* b_out = (const float*)d_in[4];

  float* out   = (float*)d_out;
  float* probs = out + 3145728;

  unsigned short* qkv_ws  = (unsigned short*)d_ws;          // bf16 [4096][2304]
  unsigned short* attn_ws = qkv_ws + (size_t)4096 * 2304;   // bf16 [4096][768]

  gemm_bias_kernel<false, true><<<dim3(18, 32), 256, 0, stream>>>(
      (const void*)x, w_qkv, b_qkv, (void*)qkv_ws, 4096, 2304, 768);

  attn_kernel<<<dim3(24, 32), 256, 0, stream>>>(qkv_ws, probs, attn_ws);

  gemm_bias_kernel<true, false><<<dim3(6, 32), 256, 0, stream>>>(
      (const void*)attn_ws, w_out, b_out, (void*)out, 4096, 768, 768);
}